// Round 13
// baseline (103.933 us; speedup 1.0000x reference)
//
#include <hip/hip_runtime.h>
#include <cmath>

// ROIAlignV2 multi-level FPN pooler. fp32 in/out.
// R13: hybrid staging. f1-f3: dense NCHW->NHWC bf16 transpose (R8-proven).
// f0 (75% of bytes): NO dense transpose; per-box window staging for L0 boxes.
// Unified NHWC pool (512B contiguous taps).
constexpr int OUTD = 14;
constexpr int NBIN = OUTD * OUTD;   // 196
constexpr int NS   = 28;            // samples per axis
constexpr int CTOT = 256;           // channels
constexpr int SLOT = 1280;          // px per L0 box window (worst ~1200)

// ws layout (ushort elems): L0 windows [M=256][SLOT][256ch], then dense f1-3
constexpr size_t OFFW = 0;
constexpr size_t OFF1 = (size_t)256 * SLOT * CTOT;        // 83,886,080
constexpr size_t OFF2 = OFF1 + 2u*16384*256;              // +8,388,608
constexpr size_t OFF3 = OFF2 + 2u*4096*256;               // +2,097,152
constexpr size_t WS_USHORT = OFF3 + 2u*1024*256;          // 94,896,128 (181 MB)
constexpr size_t WS_NEED = WS_USHORT * 2;

typedef unsigned int u32x2 __attribute__((ext_vector_type(2)));

__device__ inline int box_level(const float* __restrict__ boxes, int m,
                                float& bx0, float& by0, float& bx1, float& by1)
{
    bx0 = boxes[m*4+0]; by0 = boxes[m*4+1];
    bx1 = boxes[m*4+2]; by1 = boxes[m*4+3];
    const float size = sqrtf((bx1-bx0)*(by1-by0));
    float lf = floorf(4.0f + log2f(size/224.0f + 2.220446049250313e-16f));
    lf = fminf(fmaxf(lf, 2.0f), 5.0f);
    return (int)lf - 2;             // 0..3
}

// touched coordinate range: lo0 and extent (same math as pool taps)
__device__ inline void axis_window(float c0, float c1, int HW, int& lo, int& ext)
{
    const float binw = (c1 - c0) * (1.0f/OUTD);
    const float HWm1 = (float)(HW-1);
    const float pL = fminf(fmaxf(c0 + 0.25f*binw, 0.f), HWm1);   // sample 0
    const float pH = fminf(fmaxf(c0 + 13.75f*binw, 0.f), HWm1);  // sample 27
    const int loL = (int)floorf(pL);
    const int hiH = min((int)floorf(pH) + 1, HW - 1);
    lo = loL;
    ext = hiH - loL + 1;
}

__device__ inline float b2f(unsigned short u) {
    return __uint_as_float(((unsigned int)u) << 16);
}
__device__ inline unsigned short f2b(float x) {           // RTNE
    unsigned int u = __float_as_uint(x);
    return (unsigned short)((u + 0x7FFFu + ((u >> 16) & 1u)) >> 16);
}

// ---- Pass W: per-box window staging for L0 boxes, f0 -> [m][px][256] bf16 --
// grid (M, 2): half = 128 channels. 1024 threads, 16 waves x 8 ch.
__global__ __launch_bounds__(1024) void stage_l0(
    const float* __restrict__ f0, const float* __restrict__ boxes,
    const int* __restrict__ bidx, unsigned short* __restrict__ ws)
{
    const int m = blockIdx.x, half = blockIdx.y;
    float bx0, by0, bx1, by1;
    if (box_level(boxes, m, bx0, by0, bx1, by1) != 0) return;
    const int HW = 256;
    const float scale = 0.25f;
    int x0, ww, y0, wh;
    axis_window(bx0*scale - 0.5f, bx1*scale - 0.5f, HW, x0, ww);
    axis_window(by0*scale - 0.5f, by1*scale - 0.5f, HW, y0, wh);
    int area = ww * wh;
    if (area > SLOT) { wh = SLOT / ww; area = ww * wh; }   // never in practice
    const int b = bidx[m];

    __shared__ int s_goff[SLOT];
    __shared__ unsigned short tl[128 * 66];   // [ch][px], chunk=64, pad 2

    const int t = threadIdx.x, w = t >> 6, lane = t & 63;
    for (int e = t; e < area; e += 1024) {
        const int y = e / ww, x = e - y*ww;
        s_goff[e] = (y0 + y)*HW + x0 + x;
    }
    __syncthreads();

    const float* base = f0 + (size_t)(b*CTOT + half*128) * HW*HW;
    unsigned short* d = ws + OFFW + (size_t)m * SLOT * CTOT + half*128;

    for (int c0 = 0; c0 < area; c0 += 64) {
        const int n = min(64, area - c0);
        // A: wave w stages ch 8w..8w+7, lanes over px
        #pragma unroll
        for (int r = 0; r < 8; ++r) {
            const int ch = w*8 + r;
            if (lane < n) {
                const float v = base[(size_t)ch*HW*HW + s_goff[c0 + lane]];
                tl[ch*66 + lane] = f2b(v);
            }
        }
        __syncthreads();
        // B: 16B units (px, q of 16): 8 consecutive ch packed; 256B/px run
        for (int u = t; u < n*16; u += 1024) {
            const int px = u >> 4, q = u & 15;
            const int cb = q*8;
            uint4 val;
            val.x = (unsigned int)tl[(cb+0)*66+px] | ((unsigned int)tl[(cb+1)*66+px] << 16);
            val.y = (unsigned int)tl[(cb+2)*66+px] | ((unsigned int)tl[(cb+3)*66+px] << 16);
            val.z = (unsigned int)tl[(cb+4)*66+px] | ((unsigned int)tl[(cb+5)*66+px] << 16);
            val.w = (unsigned int)tl[(cb+6)*66+px] | ((unsigned int)tl[(cb+7)*66+px] << 16);
            *(uint4*)(d + (size_t)(c0 + px)*CTOT + cb) = val;
        }
        __syncthreads();
    }
}

// ---- Pass T: dense transpose NCHW fp32 -> NHWC bf16 for f1-f3 (R8-proven) --
// 1024 threads, tile = 256 ch x 64 px. grid: f1:512, f2:128, f3:32 = 672
__global__ __launch_bounds__(1024) void transpose_kernel(
    const float* __restrict__ f1, const float* __restrict__ f2,
    const float* __restrict__ f3, unsigned short* __restrict__ ws)
{
    const int id = blockIdx.x;
    const float* src; size_t offs; int HWsq, rem, tshift;
    if (id < 512)      { src = f1; offs = OFF1; HWsq = 16384; rem = id;       tshift = 8; }
    else if (id < 640) { src = f2; offs = OFF2; HWsq = 4096;  rem = id - 512; tshift = 6; }
    else               { src = f3; offs = OFF3; HWsq = 1024;  rem = id - 640; tshift = 4; }
    const int tile = rem & ((1 << tshift) - 1);
    const int b    = rem >> tshift;
    const int px0  = tile << 6;

    __shared__ unsigned short tl[64][264];   // [px][ch]
    const int t = threadIdx.x;

    const float* s = src + (size_t)b*CTOT*HWsq + px0;
    #pragma unroll
    for (int r = 0; r < 4; ++r) {
        const int ch = r*64 + (t >> 4);
        const int px = (t & 15) * 4;
        const float4 v = *(const float4*)(s + (size_t)ch*HWsq + px);
        tl[px+0][ch] = f2b(v.x);
        tl[px+1][ch] = f2b(v.y);
        tl[px+2][ch] = f2b(v.z);
        tl[px+3][ch] = f2b(v.w);
    }
    __syncthreads();
    unsigned short* d = ws + offs + ((size_t)b * HWsq + px0) * CTOT;
    #pragma unroll
    for (int r = 0; r < 2; ++r) {
        const int px  = r*32 + (t >> 5);
        const int c16 = (t & 31) * 8;
        const uint4 val = *(const uint4*)&tl[px][c16];
        *(uint4*)(d + (size_t)px*CTOT + c16) = val;
    }
}

// ---- Pass P: unified pool; L0 from window slots, L1-3 from dense ws ----
__global__ __launch_bounds__(256) void pool_nhwc(
    const float* __restrict__ boxes, const int* __restrict__ bidx,
    const unsigned short* __restrict__ ws, float* __restrict__ out)
{
    const int m  = blockIdx.x;
    const int bb = blockIdx.y;          // bins [28bb, 28bb+28)
    float bx0, by0, bx1, by1;
    const int L = box_level(boxes, m, bx0, by0, bx1, by1);
    const int HW = 256 >> L;
    const float scale = (L==0) ? 0.25f : (L==1) ? 0.125f : (L==2) ? 0.0625f : 0.03125f;
    const int b = bidx[m];

    int x0, ww, y0, wh;
    axis_window(bx0*scale - 0.5f, bx1*scale - 0.5f, HW, x0, ww);
    axis_window(by0*scale - 0.5f, by1*scale - 0.5f, HW, y0, wh);

    const unsigned short* mbase;
    int rowstr;
    if (L == 0) {
        mbase = ws + OFFW + (size_t)m * SLOT * CTOT;
        rowstr = ww * CTOT;
    } else {
        const size_t offs = (L==1) ? OFF1 : (L==2) ? OFF2 : OFF3;
        mbase = ws + offs + (size_t)b * HW * HW * CTOT;
        rowstr = HW * CTOT;
    }

    __shared__ int4  s_tab[2][NS];      // {lo, hi, wl, wh} (window-rel if L0)
    __shared__ float obuf[28 * 257];

    const int t = threadIdx.x, wave = t >> 6, lane = t & 63;
    if (t < 2*NS) {
        const int axis = t / NS, s = t % NS;
        const float c0 = (axis ? by0 : bx0) * scale - 0.5f;
        const float c1 = (axis ? by1 : bx1) * scale - 0.5f;
        const float binw = (c1 - c0) * (1.0f/OUTD);
        const float g = (float)(s >> 1) + ((s & 1) ? 0.75f : 0.25f);
        const float p = c0 + g * binw;
        const bool valid = (p > -1.0f) && (p < (float)HW);
        const float pc = fminf(fmaxf(p, 0.0f), (float)(HW - 1));
        int lo = (int)floorf(pc);
        int hi = min(lo + 1, HW - 1);
        const float l = pc - (float)lo;
        if (L == 0) { const int o = axis ? y0 : x0; lo -= o; hi -= o; }
        int4 e; e.x = lo; e.y = hi;
        e.z = __float_as_int(valid ? (1.0f - l) : 0.0f);
        e.w = __float_as_int(valid ? l : 0.0f);
        s_tab[axis][s] = e;
    }
    __syncthreads();

    for (int lb = 7*wave; lb < 7*wave + 7; ++lb) {
        const int bin = 28*bb + lb;
        const int ph = bin / OUTD, pw = bin - ph*OUTD;
        const int4 ty0 = s_tab[1][2*ph], ty1 = s_tab[1][2*ph+1];
        const int4 tx0 = s_tab[0][2*pw], tx1 = s_tab[0][2*pw+1];
        int ro[4]; float wy[4];
        ro[0]=ty0.x*rowstr; wy[0]=__int_as_float(ty0.z);
        ro[1]=ty0.y*rowstr; wy[1]=__int_as_float(ty0.w);
        ro[2]=ty1.x*rowstr; wy[2]=__int_as_float(ty1.z);
        ro[3]=ty1.y*rowstr; wy[3]=__int_as_float(ty1.w);
        int co[4]; float wx[4];
        co[0]=tx0.x*CTOT; wx[0]=__int_as_float(tx0.z);
        co[1]=tx0.y*CTOT; wx[1]=__int_as_float(tx0.w);
        co[2]=tx1.x*CTOT; wx[2]=__int_as_float(tx1.z);
        co[3]=tx1.y*CTOT; wx[3]=__int_as_float(tx1.w);

        ushort4 v[16]; float wt[16];
        #pragma unroll
        for (int k = 0; k < 16; ++k) {
            const unsigned short* p = mbase + (size_t)(ro[k>>2] + co[k&3]) + 4*lane;
            v[k] = *(const ushort4*)p;
            wt[k] = wy[k>>2] * wx[k&3];
        }
        float4 a0, a1, a2, a3;
        a0.x=a0.y=a0.z=a0.w=0.f; a1=a0; a2=a0; a3=a0;
        #pragma unroll
        for (int k = 0; k < 16; k += 4) {
            a0.x=fmaf(wt[k],  b2f(v[k].x),  a0.x); a0.y=fmaf(wt[k],  b2f(v[k].y),  a0.y);
            a0.z=fmaf(wt[k],  b2f(v[k].z),  a0.z); a0.w=fmaf(wt[k],  b2f(v[k].w),  a0.w);
            a1.x=fmaf(wt[k+1],b2f(v[k+1].x),a1.x); a1.y=fmaf(wt[k+1],b2f(v[k+1].y),a1.y);
            a1.z=fmaf(wt[k+1],b2f(v[k+1].z),a1.z); a1.w=fmaf(wt[k+1],b2f(v[k+1].w),a1.w);
            a2.x=fmaf(wt[k+2],b2f(v[k+2].x),a2.x); a2.y=fmaf(wt[k+2],b2f(v[k+2].y),a2.y);
            a2.z=fmaf(wt[k+2],b2f(v[k+2].z),a2.z); a2.w=fmaf(wt[k+2],b2f(v[k+2].w),a2.w);
            a3.x=fmaf(wt[k+3],b2f(v[k+3].x),a3.x); a3.y=fmaf(wt[k+3],b2f(v[k+3].y),a3.y);
            a3.z=fmaf(wt[k+3],b2f(v[k+3].z),a3.z); a3.w=fmaf(wt[k+3],b2f(v[k+3].w),a3.w);
        }
        a0.x += a1.x + a2.x + a3.x;  a0.y += a1.y + a2.y + a3.y;
        a0.z += a1.z + a2.z + a3.z;  a0.w += a1.w + a2.w + a3.w;
        float* ob = obuf + lb*257;
        ob[4*lane+0] = a0.x*0.25f; ob[4*lane+1] = a0.y*0.25f;
        ob[4*lane+2] = a0.z*0.25f; ob[4*lane+3] = a0.w*0.25f;
    }
    __syncthreads();

    for (int s = t; s < 28*CTOT; s += 256) {
        const int c = s / 28, bp = s - 28*c;
        out[((size_t)(m*CTOT + c))*NBIN + 28*bb + bp] = obuf[bp*257 + c];
    }
}

// ---- fallback: direct gather (R2-proven), all boxes ----
__global__ __launch_bounds__(256) void roi_pool_direct(
    const float* __restrict__ f0, const float* __restrict__ f1,
    const float* __restrict__ f2, const float* __restrict__ f3,
    const float* __restrict__ boxes, const int* __restrict__ bidx,
    float* __restrict__ out)
{
    const int m  = blockIdx.x;
    const int cg = blockIdx.y;
    float bx0, by0, bx1, by1;
    const int L = box_level(boxes, m, bx0, by0, bx1, by1);
    const float scale = (L==0)?0.25f:(L==1)?0.125f:(L==2)?0.0625f:0.03125f;
    const int HW = 256 >> L;
    const float* feat = (L==0)?f0:(L==1)?f1:(L==2)?f2:f3;
    const int b = bidx[m];

    __shared__ int4 s_tab[2][NS];
    const int t = threadIdx.x;
    if (t < 2*NS) {
        const int axis = t / NS, s = t % NS;
        const float c0 = (axis ? by0 : bx0) * scale - 0.5f;
        const float c1 = (axis ? by1 : bx1) * scale - 0.5f;
        const float binw = (c1 - c0) * (1.0f/OUTD);
        const float g = (float)(s >> 1) + ((s & 1) ? 0.75f : 0.25f);
        const float p = c0 + g * binw;
        const bool valid = (p > -1.0f) && (p < (float)HW);
        const float pc = fminf(fmaxf(p, 0.0f), (float)(HW - 1));
        const int lo = (int)floorf(pc);
        const int hi = min(lo + 1, HW - 1);
        const float l = pc - (float)lo;
        int4 e; e.x = lo; e.y = hi;
        e.z = __float_as_int(valid ? (1.0f - l) : 0.0f);
        e.w = __float_as_int(valid ? l : 0.0f);
        s_tab[axis][s] = e;
    }
    __syncthreads();

    const int W = HW;
    const size_t cs = (size_t)HW*HW;
    const float* gbase = feat + (size_t)(b*CTOT + cg*32)*cs;
    for (int i = t; i < 16*NBIN; i += 256) {
        const int cl = i / NBIN, bin = i - cl*NBIN;
        const int ph = bin / OUTD, pw = bin - ph*OUTD;
        const int4 ty0 = s_tab[1][2*ph], ty1 = s_tab[1][2*ph+1];
        const int4 tx0 = s_tab[0][2*pw], tx1 = s_tab[0][2*pw+1];
        int rs[4]; float wy[4];
        rs[0]=ty0.x*W; wy[0]=__int_as_float(ty0.z);
        rs[1]=ty0.y*W; wy[1]=__int_as_float(ty0.w);
        rs[2]=ty1.x*W; wy[2]=__int_as_float(ty1.z);
        rs[3]=ty1.y*W; wy[3]=__int_as_float(ty1.w);
        int cx[4]; float wx[4];
        cx[0]=tx0.x; wx[0]=__int_as_float(tx0.z);
        cx[1]=tx0.y; wx[1]=__int_as_float(tx0.w);
        cx[2]=tx1.x; wx[2]=__int_as_float(tx1.z);
        cx[3]=tx1.y; wx[3]=__int_as_float(tx1.w);
        const float* b0 = gbase + (size_t)cl*cs;
        const float* b1 = b0 + (size_t)16*cs;
        float v0[16], v1[16], w[16];
        #pragma unroll
        for (int k = 0; k < 16; ++k) {
            const int off = rs[k>>2] + cx[k&3];
            v0[k] = b0[off]; v1[k] = b1[off];
            w[k] = wy[k>>2]*wx[k&3];
        }
        float A0=0.f, A1=0.f;
        #pragma unroll
        for (int k = 0; k < 16; ++k) { A0 += w[k]*v0[k]; A1 += w[k]*v1[k]; }
        const size_t ob = ((size_t)m*CTOT + cg*32 + cl)*NBIN + bin;
        out[ob] = A0*0.25f;
        out[ob + (size_t)16*NBIN] = A1*0.25f;
    }
}

extern "C" void kernel_launch(void* const* d_in, const int* in_sizes, int n_in,
                              void* d_out, int out_size, void* d_ws, size_t ws_size,
                              hipStream_t stream) {
    const float* f0    = (const float*)d_in[0];
    const float* f1    = (const float*)d_in[1];
    const float* f2    = (const float*)d_in[2];
    const float* f3    = (const float*)d_in[3];
    const float* boxes = (const float*)d_in[4];
    const int*   bidx  = (const int*)d_in[5];
    float* out = (float*)d_out;

    const int M = in_sizes[5];
    if (ws_size >= WS_NEED) {
        unsigned short* ws = (unsigned short*)d_ws;
        stage_l0<<<dim3(M, 2), 1024, 0, stream>>>(f0, boxes, bidx, ws);
        transpose_kernel<<<672, 1024, 0, stream>>>(f1, f2, f3, ws);
        pool_nhwc<<<dim3(M, 7), 256, 0, stream>>>(boxes, bidx, ws, out);
    } else {
        roi_pool_direct<<<dim3(M, 8), 256, 0, stream>>>(f0,f1,f2,f3,boxes,bidx,out);
    }
}

// Round 14
// 98.391 us; speedup vs baseline: 1.0563x; 1.0563x over previous
//
#include <hip/hip_runtime.h>
#include <cmath>

// ROIAlignV2 multi-level FPN pooler. fp32 in/out.
// R14: fused staging kernel: dense NCHW->NHWC bf16 transpose for f1-f3
// (R6-proven tiles) + chunked per-box window staging for L0 boxes (f0 never
// densely transposed). Unified NHWC pool (512B contiguous taps).
constexpr int OUTD = 14;
constexpr int NBIN = OUTD * OUTD;   // 196
constexpr int NS   = 28;            // samples per axis
constexpr int CTOT = 256;           // channels
constexpr int SLOT = 1280;          // px per L0 box window (worst ~1100)
constexpr int CHK  = 80;            // px per L0 staging chunk (16 chunks)

// ws layout (ushort elems): L0 windows [M=256][SLOT][256ch], then dense f1-3
constexpr size_t OFFW = 0;
constexpr size_t OFF1 = (size_t)256 * SLOT * CTOT;        // 83,886,080
constexpr size_t OFF2 = OFF1 + 2u*16384*256;
constexpr size_t OFF3 = OFF2 + 2u*4096*256;
constexpr size_t WS_USHORT = OFF3 + 2u*1024*256;          // ~190 MB total
constexpr size_t WS_NEED = WS_USHORT * 2;

__device__ inline int box_level(const float* __restrict__ boxes, int m,
                                float& bx0, float& by0, float& bx1, float& by1)
{
    bx0 = boxes[m*4+0]; by0 = boxes[m*4+1];
    bx1 = boxes[m*4+2]; by1 = boxes[m*4+3];
    const float size = sqrtf((bx1-bx0)*(by1-by0));
    float lf = floorf(4.0f + log2f(size/224.0f + 2.220446049250313e-16f));
    lf = fminf(fmaxf(lf, 2.0f), 5.0f);
    return (int)lf - 2;             // 0..3
}

__device__ inline void axis_window(float c0, float c1, int HW, int& lo, int& ext)
{
    const float binw = (c1 - c0) * (1.0f/OUTD);
    const float HWm1 = (float)(HW-1);
    const float pL = fminf(fmaxf(c0 + 0.25f*binw, 0.f), HWm1);   // sample 0
    const float pH = fminf(fmaxf(c0 + 13.75f*binw, 0.f), HWm1);  // sample 27
    const int loL = (int)floorf(pL);
    const int hiH = min((int)floorf(pH) + 1, HW - 1);
    lo = loL;
    ext = hiH - loL + 1;
}

__device__ inline float b2f(unsigned short u) {
    return __uint_as_float(((unsigned int)u) << 16);
}
__device__ inline unsigned short f2b(float x) {           // RTNE
    unsigned int u = __float_as_uint(x);
    return (unsigned short)((u + 0x7FFFu + ((u >> 16) & 1u)) >> 16);
}

// ---- fused staging: id<2688 dense f1-3 tiles; else L0 window chunks ----
// 256 threads everywhere.
__global__ __launch_bounds__(256) void stage_kernel(
    const float* __restrict__ f0, const float* __restrict__ f1,
    const float* __restrict__ f2, const float* __restrict__ f3,
    const float* __restrict__ boxes, const int* __restrict__ bidx,
    unsigned short* __restrict__ ws)
{
    __shared__ __align__(16) char smem[CHK*258*2 + CHK*4];  // 41.6 KB
    const int t = threadIdx.x, w = t >> 6, lane = t & 63;
    const int id = blockIdx.x;

    if (id < 2688) {
        // ---- dense transpose tile: 64ch x 64px (R6-proven) ----
        const float* src; size_t offs; int HWsq, rem, tshift;
        if (id < 2048)      { src = f1; offs = OFF1; HWsq = 16384; rem = id;        tshift = 8; }
        else if (id < 2560) { src = f2; offs = OFF2; HWsq = 4096;  rem = id - 2048; tshift = 6; }
        else                { src = f3; offs = OFF3; HWsq = 1024;  rem = id - 2560; tshift = 4; }
        const int tile = rem & ((1 << tshift) - 1);
        const int cg   = (rem >> tshift) & 3;
        const int b    = rem >> (tshift + 2);
        const int px0  = tile << 6;

        float* tl = (float*)smem;                   // [64ch][65px] fp32
        const float* s = src + (size_t)(b*CTOT + cg*64) * HWsq + px0;
        #pragma unroll
        for (int r = 0; r < 16; ++r) {
            const int ch = r*4 + w;
            tl[ch*65 + lane] = s[(size_t)ch * HWsq + lane];
        }
        __syncthreads();
        unsigned short* d = ws + offs + ((size_t)b * HWsq + px0) * CTOT + cg*64;
        #pragma unroll
        for (int r = 0; r < 16; ++r) {
            const int p = r*4 + w;
            d[(size_t)p * CTOT + lane] = f2b(tl[lane*65 + p]);
        }
        return;
    }

    // ---- L0 window chunk: 256ch x <=80px of one box ----
    const int r2 = id - 2688;
    const int m = r2 >> 4, chunk = r2 & 15;
    float bx0, by0, bx1, by1;
    if (box_level(boxes, m, bx0, by0, bx1, by1) != 0) return;
    int x0, ww, y0, wh;
    axis_window(bx0*0.25f - 0.5f, bx1*0.25f - 0.5f, 256, x0, ww);
    axis_window(by0*0.25f - 0.5f, by1*0.25f - 0.5f, 256, y0, wh);
    int area = ww * wh;
    if (area > SLOT) { wh = SLOT / ww; area = ww * wh; }   // safety, never hits
    const int c0 = chunk * CHK;
    if (c0 >= area) return;
    const int n = min(CHK, area - c0);
    const int b = bidx[m];

    unsigned short* stl = (unsigned short*)smem;    // [80px][258ch pad]
    int* goff = (int*)(smem + CHK*258*2);           // [80]

    if (t < n) {
        const int p = c0 + t;
        const int row = p / ww;
        goff[t] = (y0 + row)*256 + x0 + (p - row*ww);
    }
    __syncthreads();

    const bool a1 = (64 + lane) < n;
    const int g0 = (lane < n) ? goff[lane] : goff[0];
    const int g1 = a1 ? goff[64 + lane] : goff[0];
    const float* cbase = f0 + (size_t)(b*CTOT) * 65536;

    #pragma unroll 4
    for (int ch = w; ch < CTOT; ch += 4) {
        const float* cp = cbase + (size_t)ch * 65536;
        const float v0 = cp[g0];
        const float v1 = cp[g1];
        if (lane < n) stl[lane*258 + ch] = f2b(v0);
        if (a1)       stl[(64+lane)*258 + ch] = f2b(v1);
    }
    __syncthreads();

    // store: 16B units, u = px*32 + q -> 512B contiguous per px
    unsigned short* d = ws + OFFW + ((size_t)m * SLOT + c0) * CTOT;
    for (int u = t; u < n*32; u += 256) {
        const int px = u >> 5, q = u & 31;
        const int cb = q*8;
        const unsigned short* sp = stl + px*258 + cb;
        uint4 val;
        val.x = (unsigned int)sp[0] | ((unsigned int)sp[1] << 16);
        val.y = (unsigned int)sp[2] | ((unsigned int)sp[3] << 16);
        val.z = (unsigned int)sp[4] | ((unsigned int)sp[5] << 16);
        val.w = (unsigned int)sp[6] | ((unsigned int)sp[7] << 16);
        *(uint4*)(d + (size_t)px*CTOT + cb) = val;
    }
}

// ---- Pass P: unified pool; L0 from window slots, L1-3 from dense ws ----
__global__ __launch_bounds__(256) void pool_nhwc(
    const float* __restrict__ boxes, const int* __restrict__ bidx,
    const unsigned short* __restrict__ ws, float* __restrict__ out)
{
    const int m  = blockIdx.x;
    const int bb = blockIdx.y;          // bins [28bb, 28bb+28)
    float bx0, by0, bx1, by1;
    const int L = box_level(boxes, m, bx0, by0, bx1, by1);
    const int HW = 256 >> L;
    const float scale = (L==0) ? 0.25f : (L==1) ? 0.125f : (L==2) ? 0.0625f : 0.03125f;
    const int b = bidx[m];

    int x0, ww, y0, wh;
    axis_window(bx0*scale - 0.5f, bx1*scale - 0.5f, HW, x0, ww);
    axis_window(by0*scale - 0.5f, by1*scale - 0.5f, HW, y0, wh);

    const unsigned short* mbase;
    int rowstr;
    if (L == 0) {
        mbase = ws + OFFW + (size_t)m * SLOT * CTOT;
        rowstr = ww * CTOT;
    } else {
        const size_t offs = (L==1) ? OFF1 : (L==2) ? OFF2 : OFF3;
        mbase = ws + offs + (size_t)b * HW * HW * CTOT;
        rowstr = HW * CTOT;
    }

    __shared__ int4  s_tab[2][NS];      // {lo, hi, wl, wh} (window-rel if L0)
    __shared__ float obuf[28 * 257];

    const int t = threadIdx.x, wave = t >> 6, lane = t & 63;
    if (t < 2*NS) {
        const int axis = t / NS, s = t % NS;
        const float c0 = (axis ? by0 : bx0) * scale - 0.5f;
        const float c1 = (axis ? by1 : bx1) * scale - 0.5f;
        const float binw = (c1 - c0) * (1.0f/OUTD);
        const float g = (float)(s >> 1) + ((s & 1) ? 0.75f : 0.25f);
        const float p = c0 + g * binw;
        const bool valid = (p > -1.0f) && (p < (float)HW);
        const float pc = fminf(fmaxf(p, 0.0f), (float)(HW - 1));
        int lo = (int)floorf(pc);
        int hi = min(lo + 1, HW - 1);
        const float l = pc - (float)lo;
        if (L == 0) { const int o = axis ? y0 : x0; lo -= o; hi -= o; }
        int4 e; e.x = lo; e.y = hi;
        e.z = __float_as_int(valid ? (1.0f - l) : 0.0f);
        e.w = __float_as_int(valid ? l : 0.0f);
        s_tab[axis][s] = e;
    }
    __syncthreads();

    for (int lb = 7*wave; lb < 7*wave + 7; ++lb) {
        const int bin = 28*bb + lb;
        const int ph = bin / OUTD, pw = bin - ph*OUTD;
        const int4 ty0 = s_tab[1][2*ph], ty1 = s_tab[1][2*ph+1];
        const int4 tx0 = s_tab[0][2*pw], tx1 = s_tab[0][2*pw+1];
        int ro[4]; float wy[4];
        ro[0]=ty0.x*rowstr; wy[0]=__int_as_float(ty0.z);
        ro[1]=ty0.y*rowstr; wy[1]=__int_as_float(ty0.w);
        ro[2]=ty1.x*rowstr; wy[2]=__int_as_float(ty1.z);
        ro[3]=ty1.y*rowstr; wy[3]=__int_as_float(ty1.w);
        int co[4]; float wx[4];
        co[0]=tx0.x*CTOT; wx[0]=__int_as_float(tx0.z);
        co[1]=tx0.y*CTOT; wx[1]=__int_as_float(tx0.w);
        co[2]=tx1.x*CTOT; wx[2]=__int_as_float(tx1.z);
        co[3]=tx1.y*CTOT; wx[3]=__int_as_float(tx1.w);

        ushort4 v[16]; float wt[16];
        #pragma unroll
        for (int k = 0; k < 16; ++k) {
            const unsigned short* p = mbase + (size_t)(ro[k>>2] + co[k&3]) + 4*lane;
            v[k] = *(const ushort4*)p;
            wt[k] = wy[k>>2] * wx[k&3];
        }
        float4 a0, a1, a2, a3;
        a0.x=a0.y=a0.z=a0.w=0.f; a1=a0; a2=a0; a3=a0;
        #pragma unroll
        for (int k = 0; k < 16; k += 4) {
            a0.x=fmaf(wt[k],  b2f(v[k].x),  a0.x); a0.y=fmaf(wt[k],  b2f(v[k].y),  a0.y);
            a0.z=fmaf(wt[k],  b2f(v[k].z),  a0.z); a0.w=fmaf(wt[k],  b2f(v[k].w),  a0.w);
            a1.x=fmaf(wt[k+1],b2f(v[k+1].x),a1.x); a1.y=fmaf(wt[k+1],b2f(v[k+1].y),a1.y);
            a1.z=fmaf(wt[k+1],b2f(v[k+1].z),a1.z); a1.w=fmaf(wt[k+1],b2f(v[k+1].w),a1.w);
            a2.x=fmaf(wt[k+2],b2f(v[k+2].x),a2.x); a2.y=fmaf(wt[k+2],b2f(v[k+2].y),a2.y);
            a2.z=fmaf(wt[k+2],b2f(v[k+2].z),a2.z); a2.w=fmaf(wt[k+2],b2f(v[k+2].w),a2.w);
            a3.x=fmaf(wt[k+3],b2f(v[k+3].x),a3.x); a3.y=fmaf(wt[k+3],b2f(v[k+3].y),a3.y);
            a3.z=fmaf(wt[k+3],b2f(v[k+3].z),a3.z); a3.w=fmaf(wt[k+3],b2f(v[k+3].w),a3.w);
        }
        a0.x += a1.x + a2.x + a3.x;  a0.y += a1.y + a2.y + a3.y;
        a0.z += a1.z + a2.z + a3.z;  a0.w += a1.w + a2.w + a3.w;
        float* ob = obuf + lb*257;
        ob[4*lane+0] = a0.x*0.25f; ob[4*lane+1] = a0.y*0.25f;
        ob[4*lane+2] = a0.z*0.25f; ob[4*lane+3] = a0.w*0.25f;
    }
    __syncthreads();

    for (int s = t; s < 28*CTOT; s += 256) {
        const int c = s / 28, bp = s - 28*c;
        out[((size_t)(m*CTOT + c))*NBIN + 28*bb + bp] = obuf[bp*257 + c];
    }
}

// ---- fallback: direct gather (R2-proven), all boxes ----
__global__ __launch_bounds__(256) void roi_pool_direct(
    const float* __restrict__ f0, const float* __restrict__ f1,
    const float* __restrict__ f2, const float* __restrict__ f3,
    const float* __restrict__ boxes, const int* __restrict__ bidx,
    float* __restrict__ out)
{
    const int m  = blockIdx.x;
    const int cg = blockIdx.y;
    float bx0, by0, bx1, by1;
    const int L = box_level(boxes, m, bx0, by0, bx1, by1);
    const float scale = (L==0)?0.25f:(L==1)?0.125f:(L==2)?0.0625f:0.03125f;
    const int HW = 256 >> L;
    const float* feat = (L==0)?f0:(L==1)?f1:(L==2)?f2:f3;
    const int b = bidx[m];

    __shared__ int4 s_tab[2][NS];
    const int t = threadIdx.x;
    if (t < 2*NS) {
        const int axis = t / NS, s = t % NS;
        const float c0 = (axis ? by0 : bx0) * scale - 0.5f;
        const float c1 = (axis ? by1 : bx1) * scale - 0.5f;
        const float binw = (c1 - c0) * (1.0f/OUTD);
        const float g = (float)(s >> 1) + ((s & 1) ? 0.75f : 0.25f);
        const float p = c0 + g * binw;
        const bool valid = (p > -1.0f) && (p < (float)HW);
        const float pc = fminf(fmaxf(p, 0.0f), (float)(HW - 1));
        const int lo = (int)floorf(pc);
        const int hi = min(lo + 1, HW - 1);
        const float l = pc - (float)lo;
        int4 e; e.x = lo; e.y = hi;
        e.z = __float_as_int(valid ? (1.0f - l) : 0.0f);
        e.w = __float_as_int(valid ? l : 0.0f);
        s_tab[axis][s] = e;
    }
    __syncthreads();

    const int W = HW;
    const size_t cs = (size_t)HW*HW;
    const float* gbase = feat + (size_t)(b*CTOT + cg*32)*cs;
    for (int i = t; i < 16*NBIN; i += 256) {
        const int cl = i / NBIN, bin = i - cl*NBIN;
        const int ph = bin / OUTD, pw = bin - ph*OUTD;
        const int4 ty0 = s_tab[1][2*ph], ty1 = s_tab[1][2*ph+1];
        const int4 tx0 = s_tab[0][2*pw], tx1 = s_tab[0][2*pw+1];
        int rs[4]; float wy[4];
        rs[0]=ty0.x*W; wy[0]=__int_as_float(ty0.z);
        rs[1]=ty0.y*W; wy[1]=__int_as_float(ty0.w);
        rs[2]=ty1.x*W; wy[2]=__int_as_float(ty1.z);
        rs[3]=ty1.y*W; wy[3]=__int_as_float(ty1.w);
        int cx[4]; float wx[4];
        cx[0]=tx0.x; wx[0]=__int_as_float(tx0.z);
        cx[1]=tx0.y; wx[1]=__int_as_float(tx0.w);
        cx[2]=tx1.x; wx[2]=__int_as_float(tx1.z);
        cx[3]=tx1.y; wx[3]=__int_as_float(tx1.w);
        const float* b0 = gbase + (size_t)cl*cs;
        const float* b1 = b0 + (size_t)16*cs;
        float v0[16], v1[16], w[16];
        #pragma unroll
        for (int k = 0; k < 16; ++k) {
            const int off = rs[k>>2] + cx[k&3];
            v0[k] = b0[off]; v1[k] = b1[off];
            w[k] = wy[k>>2]*wx[k&3];
        }
        float A0=0.f, A1=0.f;
        #pragma unroll
        for (int k = 0; k < 16; ++k) { A0 += w[k]*v0[k]; A1 += w[k]*v1[k]; }
        const size_t ob = ((size_t)m*CTOT + cg*32 + cl)*NBIN + bin;
        out[ob] = A0*0.25f;
        out[ob + (size_t)16*NBIN] = A1*0.25f;
    }
}

extern "C" void kernel_launch(void* const* d_in, const int* in_sizes, int n_in,
                              void* d_out, int out_size, void* d_ws, size_t ws_size,
                              hipStream_t stream) {
    const float* f0    = (const float*)d_in[0];
    const float* f1    = (const float*)d_in[1];
    const float* f2    = (const float*)d_in[2];
    const float* f3    = (const float*)d_in[3];
    const float* boxes = (const float*)d_in[4];
    const int*   bidx  = (const int*)d_in[5];
    float* out = (float*)d_out;

    const int M = in_sizes[5];
    if (ws_size >= WS_NEED) {
        unsigned short* ws = (unsigned short*)d_ws;
        stage_kernel<<<2688 + 16*M, 256, 0, stream>>>(f0,f1,f2,f3,boxes,bidx,ws);
        pool_nhwc<<<dim3(M, 7), 256, 0, stream>>>(boxes, bidx, ws, out);
    } else {
        roi_pool_direct<<<dim3(M, 8), 256, 0, stream>>>(f0,f1,f2,f3,boxes,bidx,out);
    }
}

// Round 15
// 61.934 us; speedup vs baseline: 1.6781x; 1.5886x over previous
//
#include <hip/hip_runtime.h>
#include <cmath>

// ROIAlignV2 multi-level FPN pooler. fp32 in/out.
// R15: fused staging (dense f1-3 transpose + L0 per-box windows) with
// union LDS (16.6KB), 576 active L0 blocks, 8-deep gather ILP.
constexpr int OUTD = 14;
constexpr int NBIN = OUTD * OUTD;   // 196
constexpr int NS   = 28;            // samples per axis
constexpr int CTOT = 256;           // channels
constexpr int SLOT = 1280;          // px per L0 box window (worst ~992)

// ws layout (ushort elems): L0 windows [M=256][SLOT][256ch], then dense f1-3
constexpr size_t OFFW = 0;
constexpr size_t OFF1 = (size_t)256 * SLOT * CTOT;
constexpr size_t OFF2 = OFF1 + 2u*16384*256;
constexpr size_t OFF3 = OFF2 + 2u*4096*256;
constexpr size_t WS_USHORT = OFF3 + 2u*1024*256;
constexpr size_t WS_NEED = WS_USHORT * 2;     // ~190 MB

__device__ inline int box_level(const float* __restrict__ boxes, int m,
                                float& bx0, float& by0, float& bx1, float& by1)
{
    bx0 = boxes[m*4+0]; by0 = boxes[m*4+1];
    bx1 = boxes[m*4+2]; by1 = boxes[m*4+3];
    const float size = sqrtf((bx1-bx0)*(by1-by0));
    float lf = floorf(4.0f + log2f(size/224.0f + 2.220446049250313e-16f));
    lf = fminf(fmaxf(lf, 2.0f), 5.0f);
    return (int)lf - 2;             // 0..3
}

__device__ inline void axis_window(float c0, float c1, int HW, int& lo, int& ext)
{
    const float binw = (c1 - c0) * (1.0f/OUTD);
    const float HWm1 = (float)(HW-1);
    const float pL = fminf(fmaxf(c0 + 0.25f*binw, 0.f), HWm1);   // sample 0
    const float pH = fminf(fmaxf(c0 + 13.75f*binw, 0.f), HWm1);  // sample 27
    const int loL = (int)floorf(pL);
    const int hiH = min((int)floorf(pH) + 1, HW - 1);
    lo = loL;
    ext = hiH - loL + 1;
}

__device__ inline float b2f(unsigned short u) {
    return __uint_as_float(((unsigned int)u) << 16);
}
__device__ inline unsigned short f2b(float x) {           // RTNE
    unsigned int u = __float_as_uint(x);
    return (unsigned short)((u + 0x7FFFu + ((u >> 16) & 1u)) >> 16);
}

// ---- fused staging: id<2688 dense f1-3 tiles; else L0 window chunks ----
// 256 threads. smem union: dense 16.64KB fp32 tile / L0 6.9KB.
__global__ __launch_bounds__(256) void stage_kernel(
    const float* __restrict__ f0, const float* __restrict__ f1,
    const float* __restrict__ f2, const float* __restrict__ f3,
    const float* __restrict__ boxes, const int* __restrict__ bidx,
    unsigned short* __restrict__ ws)
{
    __shared__ __align__(16) char smem[16640];
    const int t = threadIdx.x, w = t >> 6, lane = t & 63;
    const int id = blockIdx.x;

    if (id < 2688) {
        // ---- dense transpose tile: 64ch x 64px (R6-proven) ----
        const float* src; size_t offs; int HWsq, rem, tshift;
        if (id < 2048)      { src = f1; offs = OFF1; HWsq = 16384; rem = id;        tshift = 8; }
        else if (id < 2560) { src = f2; offs = OFF2; HWsq = 4096;  rem = id - 2048; tshift = 6; }
        else                { src = f3; offs = OFF3; HWsq = 1024;  rem = id - 2560; tshift = 4; }
        const int tile = rem & ((1 << tshift) - 1);
        const int cg   = (rem >> tshift) & 3;
        const int b    = rem >> (tshift + 2);
        const int px0  = tile << 6;

        float* tl = (float*)smem;                   // [64ch][65px] fp32
        const float* s = src + (size_t)(b*CTOT + cg*64) * HWsq + px0;
        #pragma unroll
        for (int r = 0; r < 16; ++r) {
            const int ch = r*4 + w;
            tl[ch*65 + lane] = s[(size_t)ch * HWsq + lane];
        }
        __syncthreads();
        unsigned short* d = ws + offs + ((size_t)b * HWsq + px0) * CTOT + cg*64;
        #pragma unroll
        for (int r = 0; r < 16; ++r) {
            const int p = r*4 + w;
            d[(size_t)p * CTOT + lane] = f2b(tl[lane*65 + p]);
        }
        return;
    }

    // ---- L0 window: (box, 32-ch group, window half) ----
    const int r2 = id - 2688;
    const int m = r2 >> 4, sub = r2 & 15;
    const int cg = sub & 7, hf = sub >> 3;
    float bx0, by0, bx1, by1;
    if (box_level(boxes, m, bx0, by0, bx1, by1) != 0) return;
    int x0, ww, y0, wh;
    axis_window(bx0*0.25f - 0.5f, bx1*0.25f - 0.5f, 256, x0, ww);
    axis_window(by0*0.25f - 0.5f, by1*0.25f - 0.5f, 256, y0, wh);
    int area = ww * wh;
    if (area > SLOT) { wh = SLOT / ww; area = ww * wh; }   // safety, never hits
    const int halfsz = (area + 1) >> 1;
    const int p0 = hf * halfsz;
    const int cnt = min(area, p0 + halfsz) - p0;
    if (cnt <= 0) return;
    const int b = bidx[m];

    unsigned short* stl = (unsigned short*)smem;     // [64px][34ch pad]
    int* goff = (int*)(smem + 64*34*2);              // [<=640]

    for (int e = t; e < cnt; e += 256) {
        const int p = p0 + e;
        const int row = p / ww;
        goff[e] = (y0 + row)*256 + x0 + (p - row*ww);
    }
    __syncthreads();

    const float* cb = f0 + (size_t)(b*CTOT + cg*32 + w*8) * 65536;
    unsigned short* d = ws + OFFW + ((size_t)m * SLOT + p0) * CTOT + cg*32;

    for (int c0 = 0; c0 < cnt; c0 += 64) {
        const int n = min(64, cnt - c0);
        if (lane < n) {
            const int g = goff[c0 + lane];
            float v[8];
            #pragma unroll
            for (int r = 0; r < 8; ++r) v[r] = cb[(size_t)r*65536 + g];
            #pragma unroll
            for (int r = 0; r < 8; ++r) stl[lane*34 + w*8 + r] = f2b(v[r]);
        }
        __syncthreads();
        for (int u = t; u < n*4; u += 256) {
            const int px = u >> 2, q = u & 3;
            const unsigned short* sp = stl + px*34 + q*8;
            uint4 val;
            val.x = (unsigned int)sp[0] | ((unsigned int)sp[1] << 16);
            val.y = (unsigned int)sp[2] | ((unsigned int)sp[3] << 16);
            val.z = (unsigned int)sp[4] | ((unsigned int)sp[5] << 16);
            val.w = (unsigned int)sp[6] | ((unsigned int)sp[7] << 16);
            *(uint4*)(d + (size_t)(c0 + px)*CTOT + q*8) = val;
        }
        __syncthreads();
    }
}

// ---- Pass P: unified pool; L0 from window slots, L1-3 from dense ws ----
__global__ __launch_bounds__(256) void pool_nhwc(
    const float* __restrict__ boxes, const int* __restrict__ bidx,
    const unsigned short* __restrict__ ws, float* __restrict__ out)
{
    const int m  = blockIdx.x;
    const int bb = blockIdx.y;          // bins [28bb, 28bb+28)
    float bx0, by0, bx1, by1;
    const int L = box_level(boxes, m, bx0, by0, bx1, by1);
    const int HW = 256 >> L;
    const float scale = (L==0) ? 0.25f : (L==1) ? 0.125f : (L==2) ? 0.0625f : 0.03125f;
    const int b = bidx[m];

    int x0, ww, y0, wh;
    axis_window(bx0*scale - 0.5f, bx1*scale - 0.5f, HW, x0, ww);
    axis_window(by0*scale - 0.5f, by1*scale - 0.5f, HW, y0, wh);

    const unsigned short* mbase;
    int rowstr;
    if (L == 0) {
        mbase = ws + OFFW + (size_t)m * SLOT * CTOT;
        rowstr = ww * CTOT;
    } else {
        const size_t offs = (L==1) ? OFF1 : (L==2) ? OFF2 : OFF3;
        mbase = ws + offs + (size_t)b * HW * HW * CTOT;
        rowstr = HW * CTOT;
    }

    __shared__ int4  s_tab[2][NS];      // {lo, hi, wl, wh} (window-rel if L0)
    __shared__ float obuf[28 * 257];

    const int t = threadIdx.x, wave = t >> 6, lane = t & 63;
    if (t < 2*NS) {
        const int axis = t / NS, s = t % NS;
        const float c0 = (axis ? by0 : bx0) * scale - 0.5f;
        const float c1 = (axis ? by1 : bx1) * scale - 0.5f;
        const float binw = (c1 - c0) * (1.0f/OUTD);
        const float g = (float)(s >> 1) + ((s & 1) ? 0.75f : 0.25f);
        const float p = c0 + g * binw;
        const bool valid = (p > -1.0f) && (p < (float)HW);
        const float pc = fminf(fmaxf(p, 0.0f), (float)(HW - 1));
        int lo = (int)floorf(pc);
        int hi = min(lo + 1, HW - 1);
        const float l = pc - (float)lo;
        if (L == 0) { const int o = axis ? y0 : x0; lo -= o; hi -= o; }
        int4 e; e.x = lo; e.y = hi;
        e.z = __float_as_int(valid ? (1.0f - l) : 0.0f);
        e.w = __float_as_int(valid ? l : 0.0f);
        s_tab[axis][s] = e;
    }
    __syncthreads();

    for (int lb = 7*wave; lb < 7*wave + 7; ++lb) {
        const int bin = 28*bb + lb;
        const int ph = bin / OUTD, pw = bin - ph*OUTD;
        const int4 ty0 = s_tab[1][2*ph], ty1 = s_tab[1][2*ph+1];
        const int4 tx0 = s_tab[0][2*pw], tx1 = s_tab[0][2*pw+1];
        int ro[4]; float wy[4];
        ro[0]=ty0.x*rowstr; wy[0]=__int_as_float(ty0.z);
        ro[1]=ty0.y*rowstr; wy[1]=__int_as_float(ty0.w);
        ro[2]=ty1.x*rowstr; wy[2]=__int_as_float(ty1.z);
        ro[3]=ty1.y*rowstr; wy[3]=__int_as_float(ty1.w);
        int co[4]; float wx[4];
        co[0]=tx0.x*CTOT; wx[0]=__int_as_float(tx0.z);
        co[1]=tx0.y*CTOT; wx[1]=__int_as_float(tx0.w);
        co[2]=tx1.x*CTOT; wx[2]=__int_as_float(tx1.z);
        co[3]=tx1.y*CTOT; wx[3]=__int_as_float(tx1.w);

        ushort4 v[16]; float wt[16];
        #pragma unroll
        for (int k = 0; k < 16; ++k) {
            const unsigned short* p = mbase + (size_t)(ro[k>>2] + co[k&3]) + 4*lane;
            v[k] = *(const ushort4*)p;
            wt[k] = wy[k>>2] * wx[k&3];
        }
        float4 a0, a1, a2, a3;
        a0.x=a0.y=a0.z=a0.w=0.f; a1=a0; a2=a0; a3=a0;
        #pragma unroll
        for (int k = 0; k < 16; k += 4) {
            a0.x=fmaf(wt[k],  b2f(v[k].x),  a0.x); a0.y=fmaf(wt[k],  b2f(v[k].y),  a0.y);
            a0.z=fmaf(wt[k],  b2f(v[k].z),  a0.z); a0.w=fmaf(wt[k],  b2f(v[k].w),  a0.w);
            a1.x=fmaf(wt[k+1],b2f(v[k+1].x),a1.x); a1.y=fmaf(wt[k+1],b2f(v[k+1].y),a1.y);
            a1.z=fmaf(wt[k+1],b2f(v[k+1].z),a1.z); a1.w=fmaf(wt[k+1],b2f(v[k+1].w),a1.w);
            a2.x=fmaf(wt[k+2],b2f(v[k+2].x),a2.x); a2.y=fmaf(wt[k+2],b2f(v[k+2].y),a2.y);
            a2.z=fmaf(wt[k+2],b2f(v[k+2].z),a2.z); a2.w=fmaf(wt[k+2],b2f(v[k+2].w),a2.w);
            a3.x=fmaf(wt[k+3],b2f(v[k+3].x),a3.x); a3.y=fmaf(wt[k+3],b2f(v[k+3].y),a3.y);
            a3.z=fmaf(wt[k+3],b2f(v[k+3].z),a3.z); a3.w=fmaf(wt[k+3],b2f(v[k+3].w),a3.w);
        }
        a0.x += a1.x + a2.x + a3.x;  a0.y += a1.y + a2.y + a3.y;
        a0.z += a1.z + a2.z + a3.z;  a0.w += a1.w + a2.w + a3.w;
        float* ob = obuf + lb*257;
        ob[4*lane+0] = a0.x*0.25f; ob[4*lane+1] = a0.y*0.25f;
        ob[4*lane+2] = a0.z*0.25f; ob[4*lane+3] = a0.w*0.25f;
    }
    __syncthreads();

    for (int s = t; s < 28*CTOT; s += 256) {
        const int c = s / 28, bp = s - 28*c;
        out[((size_t)(m*CTOT + c))*NBIN + 28*bb + bp] = obuf[bp*257 + c];
    }
}

// ---- fallback: direct gather (R2-proven), all boxes ----
__global__ __launch_bounds__(256) void roi_pool_direct(
    const float* __restrict__ f0, const float* __restrict__ f1,
    const float* __restrict__ f2, const float* __restrict__ f3,
    const float* __restrict__ boxes, const int* __restrict__ bidx,
    float* __restrict__ out)
{
    const int m  = blockIdx.x;
    const int cg = blockIdx.y;
    float bx0, by0, bx1, by1;
    const int L = box_level(boxes, m, bx0, by0, bx1, by1);
    const float scale = (L==0)?0.25f:(L==1)?0.125f:(L==2)?0.0625f:0.03125f;
    const int HW = 256 >> L;
    const float* feat = (L==0)?f0:(L==1)?f1:(L==2)?f2:f3;
    const int b = bidx[m];

    __shared__ int4 s_tab[2][NS];
    const int t = threadIdx.x;
    if (t < 2*NS) {
        const int axis = t / NS, s = t % NS;
        const float c0 = (axis ? by0 : bx0) * scale - 0.5f;
        const float c1 = (axis ? by1 : bx1) * scale - 0.5f;
        const float binw = (c1 - c0) * (1.0f/OUTD);
        const float g = (float)(s >> 1) + ((s & 1) ? 0.75f : 0.25f);
        const float p = c0 + g * binw;
        const bool valid = (p > -1.0f) && (p < (float)HW);
        const float pc = fminf(fmaxf(p, 0.0f), (float)(HW - 1));
        const int lo = (int)floorf(pc);
        const int hi = min(lo + 1, HW - 1);
        const float l = pc - (float)lo;
        int4 e; e.x = lo; e.y = hi;
        e.z = __float_as_int(valid ? (1.0f - l) : 0.0f);
        e.w = __float_as_int(valid ? l : 0.0f);
        s_tab[axis][s] = e;
    }
    __syncthreads();

    const int W = HW;
    const size_t cs = (size_t)HW*HW;
    const float* gbase = feat + (size_t)(b*CTOT + cg*32)*cs;
    for (int i = t; i < 16*NBIN; i += 256) {
        const int cl = i / NBIN, bin = i - cl*NBIN;
        const int ph = bin / OUTD, pw = bin - ph*OUTD;
        const int4 ty0 = s_tab[1][2*ph], ty1 = s_tab[1][2*ph+1];
        const int4 tx0 = s_tab[0][2*pw], tx1 = s_tab[0][2*pw+1];
        int rs[4]; float wy[4];
        rs[0]=ty0.x*W; wy[0]=__int_as_float(ty0.z);
        rs[1]=ty0.y*W; wy[1]=__int_as_float(ty0.w);
        rs[2]=ty1.x*W; wy[2]=__int_as_float(ty1.z);
        rs[3]=ty1.y*W; wy[3]=__int_as_float(ty1.w);
        int cx[4]; float wx[4];
        cx[0]=tx0.x; wx[0]=__int_as_float(tx0.z);
        cx[1]=tx0.y; wx[1]=__int_as_float(tx0.w);
        cx[2]=tx1.x; wx[2]=__int_as_float(tx1.z);
        cx[3]=tx1.y; wx[3]=__int_as_float(tx1.w);
        const float* b0 = gbase + (size_t)cl*cs;
        const float* b1 = b0 + (size_t)16*cs;
        float v0[16], v1[16], w[16];
        #pragma unroll
        for (int k = 0; k < 16; ++k) {
            const int off = rs[k>>2] + cx[k&3];
            v0[k] = b0[off]; v1[k] = b1[off];
            w[k] = wy[k>>2]*wx[k&3];
        }
        float A0=0.f, A1=0.f;
        #pragma unroll
        for (int k = 0; k < 16; ++k) { A0 += w[k]*v0[k]; A1 += w[k]*v1[k]; }
        const size_t ob = ((size_t)m*CTOT + cg*32 + cl)*NBIN + bin;
        out[ob] = A0*0.25f;
        out[ob + (size_t)16*NBIN] = A1*0.25f;
    }
}

extern "C" void kernel_launch(void* const* d_in, const int* in_sizes, int n_in,
                              void* d_out, int out_size, void* d_ws, size_t ws_size,
                              hipStream_t stream) {
    const float* f0    = (const float*)d_in[0];
    const float* f1    = (const float*)d_in[1];
    const float* f2    = (const float*)d_in[2];
    const float* f3    = (const float*)d_in[3];
    const float* boxes = (const float*)d_in[4];
    const int*   bidx  = (const int*)d_in[5];
    float* out = (float*)d_out;

    const int M = in_sizes[5];
    if (ws_size >= WS_NEED) {
        unsigned short* ws = (unsigned short*)d_ws;
        stage_kernel<<<2688 + 16*M, 256, 0, stream>>>(f0,f1,f2,f3,boxes,bidx,ws);
        pool_nhwc<<<dim3(M, 7), 256, 0, stream>>>(boxes, bidx, ws, out);
    } else {
        roi_pool_direct<<<dim3(M, 8), 256, 0, stream>>>(f0,f1,f2,f3,boxes,bidx,out);
    }
}

// Round 16
// 58.579 us; speedup vs baseline: 1.7742x; 1.0573x over previous
//
#include <hip/hip_runtime.h>
#include <cmath>

// ROIAlignV2 multi-level FPN pooler. fp32 in/out.
// R16: R15 + L0-first block ordering + quarter-split L0 windows (1152 active
// L0 blocks, 5 serial iters) overlapping dense f1-3 transpose.
constexpr int OUTD = 14;
constexpr int NBIN = OUTD * OUTD;   // 196
constexpr int NS   = 28;            // samples per axis
constexpr int CTOT = 256;           // channels
constexpr int SLOT = 1280;          // px per L0 box window (worst ~992)

// ws layout (ushort elems): L0 windows [M=256][SLOT][256ch], then dense f1-3
constexpr size_t OFFW = 0;
constexpr size_t OFF1 = (size_t)256 * SLOT * CTOT;
constexpr size_t OFF2 = OFF1 + 2u*16384*256;
constexpr size_t OFF3 = OFF2 + 2u*4096*256;
constexpr size_t WS_USHORT = OFF3 + 2u*1024*256;
constexpr size_t WS_NEED = WS_USHORT * 2;     // ~190 MB

__device__ inline int box_level(const float* __restrict__ boxes, int m,
                                float& bx0, float& by0, float& bx1, float& by1)
{
    bx0 = boxes[m*4+0]; by0 = boxes[m*4+1];
    bx1 = boxes[m*4+2]; by1 = boxes[m*4+3];
    const float size = sqrtf((bx1-bx0)*(by1-by0));
    float lf = floorf(4.0f + log2f(size/224.0f + 2.220446049250313e-16f));
    lf = fminf(fmaxf(lf, 2.0f), 5.0f);
    return (int)lf - 2;             // 0..3
}

__device__ inline void axis_window(float c0, float c1, int HW, int& lo, int& ext)
{
    const float binw = (c1 - c0) * (1.0f/OUTD);
    const float HWm1 = (float)(HW-1);
    const float pL = fminf(fmaxf(c0 + 0.25f*binw, 0.f), HWm1);   // sample 0
    const float pH = fminf(fmaxf(c0 + 13.75f*binw, 0.f), HWm1);  // sample 27
    const int loL = (int)floorf(pL);
    const int hiH = min((int)floorf(pH) + 1, HW - 1);
    lo = loL;
    ext = hiH - loL + 1;
}

__device__ inline float b2f(unsigned short u) {
    return __uint_as_float(((unsigned int)u) << 16);
}
__device__ inline unsigned short f2b(float x) {           // RTNE
    unsigned int u = __float_as_uint(x);
    return (unsigned short)((u + 0x7FFFu + ((u >> 16) & 1u)) >> 16);
}

// ---- fused staging: id < 32M -> L0 window quarters (first: latency-bound);
//      else dense f1-3 transpose tiles. 256 threads; union LDS 16.64KB.
__global__ __launch_bounds__(256) void stage_kernel(
    const float* __restrict__ f0, const float* __restrict__ f1,
    const float* __restrict__ f2, const float* __restrict__ f3,
    const float* __restrict__ boxes, const int* __restrict__ bidx,
    unsigned short* __restrict__ ws, int M)
{
    __shared__ __align__(16) char smem[16640];
    const int t = threadIdx.x, w = t >> 6, lane = t & 63;
    const int id = blockIdx.x;
    const int NL0 = 32 * M;

    if (id >= NL0) {
        // ---- dense transpose tile: 64ch x 64px (R6-proven) ----
        const int id2 = id - NL0;
        const float* src; size_t offs; int HWsq, rem, tshift;
        if (id2 < 2048)      { src = f1; offs = OFF1; HWsq = 16384; rem = id2;        tshift = 8; }
        else if (id2 < 2560) { src = f2; offs = OFF2; HWsq = 4096;  rem = id2 - 2048; tshift = 6; }
        else                 { src = f3; offs = OFF3; HWsq = 1024;  rem = id2 - 2560; tshift = 4; }
        const int tile = rem & ((1 << tshift) - 1);
        const int cg   = (rem >> tshift) & 3;
        const int b    = rem >> (tshift + 2);
        const int px0  = tile << 6;

        float* tl = (float*)smem;                   // [64ch][65px] fp32
        const float* s = src + (size_t)(b*CTOT + cg*64) * HWsq + px0;
        #pragma unroll
        for (int r = 0; r < 16; ++r) {
            const int ch = r*4 + w;
            tl[ch*65 + lane] = s[(size_t)ch * HWsq + lane];
        }
        __syncthreads();
        unsigned short* d = ws + offs + ((size_t)b * HWsq + px0) * CTOT + cg*64;
        #pragma unroll
        for (int r = 0; r < 16; ++r) {
            const int p = r*4 + w;
            d[(size_t)p * CTOT + lane] = f2b(tl[lane*65 + p]);
        }
        return;
    }

    // ---- L0 window: (box, 32-ch group, window quarter) ----
    const int m = id >> 5, sub = id & 31;
    const int cg = sub & 7, qt = sub >> 3;
    float bx0, by0, bx1, by1;
    if (box_level(boxes, m, bx0, by0, bx1, by1) != 0) return;
    int x0, ww, y0, wh;
    axis_window(bx0*0.25f - 0.5f, bx1*0.25f - 0.5f, 256, x0, ww);
    axis_window(by0*0.25f - 0.5f, by1*0.25f - 0.5f, 256, y0, wh);
    int area = ww * wh;
    if (area > SLOT) { wh = SLOT / ww; area = ww * wh; }   // safety, never hits
    const int qsz = (area + 3) >> 2;
    const int p0 = qt * qsz;
    const int cnt = min(area, p0 + qsz) - p0;
    if (cnt <= 0) return;
    const int b = bidx[m];

    unsigned short* stl = (unsigned short*)smem;     // [64px][34ch pad]
    int* goff = (int*)(smem + 64*34*2);              // [<=320]

    for (int e = t; e < cnt; e += 256) {
        const int p = p0 + e;
        const int row = p / ww;
        goff[e] = (y0 + row)*256 + x0 + (p - row*ww);
    }
    __syncthreads();

    const float* cb = f0 + (size_t)(b*CTOT + cg*32 + w*8) * 65536;
    unsigned short* d = ws + OFFW + ((size_t)m * SLOT + p0) * CTOT + cg*32;

    for (int c0 = 0; c0 < cnt; c0 += 64) {
        const int n = min(64, cnt - c0);
        if (lane < n) {
            const int g = goff[c0 + lane];
            float v[8];
            #pragma unroll
            for (int r = 0; r < 8; ++r) v[r] = cb[(size_t)r*65536 + g];
            #pragma unroll
            for (int r = 0; r < 8; ++r) stl[lane*34 + w*8 + r] = f2b(v[r]);
        }
        __syncthreads();
        for (int u = t; u < n*4; u += 256) {
            const int px = u >> 2, q = u & 3;
            const unsigned short* sp = stl + px*34 + q*8;
            uint4 val;
            val.x = (unsigned int)sp[0] | ((unsigned int)sp[1] << 16);
            val.y = (unsigned int)sp[2] | ((unsigned int)sp[3] << 16);
            val.z = (unsigned int)sp[4] | ((unsigned int)sp[5] << 16);
            val.w = (unsigned int)sp[6] | ((unsigned int)sp[7] << 16);
            *(uint4*)(d + (size_t)(c0 + px)*CTOT + q*8) = val;
        }
        __syncthreads();
    }
}

// ---- Pass P: unified pool; L0 from window slots, L1-3 from dense ws ----
__global__ __launch_bounds__(256) void pool_nhwc(
    const float* __restrict__ boxes, const int* __restrict__ bidx,
    const unsigned short* __restrict__ ws, float* __restrict__ out)
{
    const int m  = blockIdx.x;
    const int bb = blockIdx.y;          // bins [28bb, 28bb+28)
    float bx0, by0, bx1, by1;
    const int L = box_level(boxes, m, bx0, by0, bx1, by1);
    const int HW = 256 >> L;
    const float scale = (L==0) ? 0.25f : (L==1) ? 0.125f : (L==2) ? 0.0625f : 0.03125f;
    const int b = bidx[m];

    int x0, ww, y0, wh;
    axis_window(bx0*scale - 0.5f, bx1*scale - 0.5f, HW, x0, ww);
    axis_window(by0*scale - 0.5f, by1*scale - 0.5f, HW, y0, wh);

    const unsigned short* mbase;
    int rowstr;
    if (L == 0) {
        mbase = ws + OFFW + (size_t)m * SLOT * CTOT;
        rowstr = ww * CTOT;
    } else {
        const size_t offs = (L==1) ? OFF1 : (L==2) ? OFF2 : OFF3;
        mbase = ws + offs + (size_t)b * HW * HW * CTOT;
        rowstr = HW * CTOT;
    }

    __shared__ int4  s_tab[2][NS];      // {lo, hi, wl, wh} (window-rel if L0)
    __shared__ float obuf[28 * 257];

    const int t = threadIdx.x, wave = t >> 6, lane = t & 63;
    if (t < 2*NS) {
        const int axis = t / NS, s = t % NS;
        const float c0 = (axis ? by0 : bx0) * scale - 0.5f;
        const float c1 = (axis ? by1 : bx1) * scale - 0.5f;
        const float binw = (c1 - c0) * (1.0f/OUTD);
        const float g = (float)(s >> 1) + ((s & 1) ? 0.75f : 0.25f);
        const float p = c0 + g * binw;
        const bool valid = (p > -1.0f) && (p < (float)HW);
        const float pc = fminf(fmaxf(p, 0.0f), (float)(HW - 1));
        int lo = (int)floorf(pc);
        int hi = min(lo + 1, HW - 1);
        const float l = pc - (float)lo;
        if (L == 0) { const int o = axis ? y0 : x0; lo -= o; hi -= o; }
        int4 e; e.x = lo; e.y = hi;
        e.z = __float_as_int(valid ? (1.0f - l) : 0.0f);
        e.w = __float_as_int(valid ? l : 0.0f);
        s_tab[axis][s] = e;
    }
    __syncthreads();

    for (int lb = 7*wave; lb < 7*wave + 7; ++lb) {
        const int bin = 28*bb + lb;
        const int ph = bin / OUTD, pw = bin - ph*OUTD;
        const int4 ty0 = s_tab[1][2*ph], ty1 = s_tab[1][2*ph+1];
        const int4 tx0 = s_tab[0][2*pw], tx1 = s_tab[0][2*pw+1];
        int ro[4]; float wy[4];
        ro[0]=ty0.x*rowstr; wy[0]=__int_as_float(ty0.z);
        ro[1]=ty0.y*rowstr; wy[1]=__int_as_float(ty0.w);
        ro[2]=ty1.x*rowstr; wy[2]=__int_as_float(ty1.z);
        ro[3]=ty1.y*rowstr; wy[3]=__int_as_float(ty1.w);
        int co[4]; float wx[4];
        co[0]=tx0.x*CTOT; wx[0]=__int_as_float(tx0.z);
        co[1]=tx0.y*CTOT; wx[1]=__int_as_float(tx0.w);
        co[2]=tx1.x*CTOT; wx[2]=__int_as_float(tx1.z);
        co[3]=tx1.y*CTOT; wx[3]=__int_as_float(tx1.w);

        ushort4 v[16]; float wt[16];
        #pragma unroll
        for (int k = 0; k < 16; ++k) {
            const unsigned short* p = mbase + (size_t)(ro[k>>2] + co[k&3]) + 4*lane;
            v[k] = *(const ushort4*)p;
            wt[k] = wy[k>>2] * wx[k&3];
        }
        float4 a0, a1, a2, a3;
        a0.x=a0.y=a0.z=a0.w=0.f; a1=a0; a2=a0; a3=a0;
        #pragma unroll
        for (int k = 0; k < 16; k += 4) {
            a0.x=fmaf(wt[k],  b2f(v[k].x),  a0.x); a0.y=fmaf(wt[k],  b2f(v[k].y),  a0.y);
            a0.z=fmaf(wt[k],  b2f(v[k].z),  a0.z); a0.w=fmaf(wt[k],  b2f(v[k].w),  a0.w);
            a1.x=fmaf(wt[k+1],b2f(v[k+1].x),a1.x); a1.y=fmaf(wt[k+1],b2f(v[k+1].y),a1.y);
            a1.z=fmaf(wt[k+1],b2f(v[k+1].z),a1.z); a1.w=fmaf(wt[k+1],b2f(v[k+1].w),a1.w);
            a2.x=fmaf(wt[k+2],b2f(v[k+2].x),a2.x); a2.y=fmaf(wt[k+2],b2f(v[k+2].y),a2.y);
            a2.z=fmaf(wt[k+2],b2f(v[k+2].z),a2.z); a2.w=fmaf(wt[k+2],b2f(v[k+2].w),a2.w);
            a3.x=fmaf(wt[k+3],b2f(v[k+3].x),a3.x); a3.y=fmaf(wt[k+3],b2f(v[k+3].y),a3.y);
            a3.z=fmaf(wt[k+3],b2f(v[k+3].z),a3.z); a3.w=fmaf(wt[k+3],b2f(v[k+3].w),a3.w);
        }
        a0.x += a1.x + a2.x + a3.x;  a0.y += a1.y + a2.y + a3.y;
        a0.z += a1.z + a2.z + a3.z;  a0.w += a1.w + a2.w + a3.w;
        float* ob = obuf + lb*257;
        ob[4*lane+0] = a0.x*0.25f; ob[4*lane+1] = a0.y*0.25f;
        ob[4*lane+2] = a0.z*0.25f; ob[4*lane+3] = a0.w*0.25f;
    }
    __syncthreads();

    for (int s = t; s < 28*CTOT; s += 256) {
        const int c = s / 28, bp = s - 28*c;
        out[((size_t)(m*CTOT + c))*NBIN + 28*bb + bp] = obuf[bp*257 + c];
    }
}

// ---- fallback: direct gather (R2-proven), all boxes ----
__global__ __launch_bounds__(256) void roi_pool_direct(
    const float* __restrict__ f0, const float* __restrict__ f1,
    const float* __restrict__ f2, const float* __restrict__ f3,
    const float* __restrict__ boxes, const int* __restrict__ bidx,
    float* __restrict__ out)
{
    const int m  = blockIdx.x;
    const int cg = blockIdx.y;
    float bx0, by0, bx1, by1;
    const int L = box_level(boxes, m, bx0, by0, bx1, by1);
    const float scale = (L==0)?0.25f:(L==1)?0.125f:(L==2)?0.0625f:0.03125f;
    const int HW = 256 >> L;
    const float* feat = (L==0)?f0:(L==1)?f1:(L==2)?f2:f3;
    const int b = bidx[m];

    __shared__ int4 s_tab[2][NS];
    const int t = threadIdx.x;
    if (t < 2*NS) {
        const int axis = t / NS, s = t % NS;
        const float c0 = (axis ? by0 : bx0) * scale - 0.5f;
        const float c1 = (axis ? by1 : bx1) * scale - 0.5f;
        const float binw = (c1 - c0) * (1.0f/OUTD);
        const float g = (float)(s >> 1) + ((s & 1) ? 0.75f : 0.25f);
        const float p = c0 + g * binw;
        const bool valid = (p > -1.0f) && (p < (float)HW);
        const float pc = fminf(fmaxf(p, 0.0f), (float)(HW - 1));
        const int lo = (int)floorf(pc);
        const int hi = min(lo + 1, HW - 1);
        const float l = pc - (float)lo;
        int4 e; e.x = lo; e.y = hi;
        e.z = __float_as_int(valid ? (1.0f - l) : 0.0f);
        e.w = __float_as_int(valid ? l : 0.0f);
        s_tab[axis][s] = e;
    }
    __syncthreads();

    const int W = HW;
    const size_t cs = (size_t)HW*HW;
    const float* gbase = feat + (size_t)(b*CTOT + cg*32)*cs;
    for (int i = t; i < 16*NBIN; i += 256) {
        const int cl = i / NBIN, bin = i - cl*NBIN;
        const int ph = bin / OUTD, pw = bin - ph*OUTD;
        const int4 ty0 = s_tab[1][2*ph], ty1 = s_tab[1][2*ph+1];
        const int4 tx0 = s_tab[0][2*pw], tx1 = s_tab[0][2*pw+1];
        int rs[4]; float wy[4];
        rs[0]=ty0.x*W; wy[0]=__int_as_float(ty0.z);
        rs[1]=ty0.y*W; wy[1]=__int_as_float(ty0.w);
        rs[2]=ty1.x*W; wy[2]=__int_as_float(ty1.z);
        rs[3]=ty1.y*W; wy[3]=__int_as_float(ty1.w);
        int cx[4]; float wx[4];
        cx[0]=tx0.x; wx[0]=__int_as_float(tx0.z);
        cx[1]=tx0.y; wx[1]=__int_as_float(tx0.w);
        cx[2]=tx1.x; wx[2]=__int_as_float(tx1.z);
        cx[3]=tx1.y; wx[3]=__int_as_float(tx1.w);
        const float* b0 = gbase + (size_t)cl*cs;
        const float* b1 = b0 + (size_t)16*cs;
        float v0[16], v1[16], w[16];
        #pragma unroll
        for (int k = 0; k < 16; ++k) {
            const int off = rs[k>>2] + cx[k&3];
            v0[k] = b0[off]; v1[k] = b1[off];
            w[k] = wy[k>>2]*wx[k&3];
        }
        float A0=0.f, A1=0.f;
        #pragma unroll
        for (int k = 0; k < 16; ++k) { A0 += w[k]*v0[k]; A1 += w[k]*v1[k]; }
        const size_t ob = ((size_t)m*CTOT + cg*32 + cl)*NBIN + bin;
        out[ob] = A0*0.25f;
        out[ob + (size_t)16*NBIN] = A1*0.25f;
    }
}

extern "C" void kernel_launch(void* const* d_in, const int* in_sizes, int n_in,
                              void* d_out, int out_size, void* d_ws, size_t ws_size,
                              hipStream_t stream) {
    const float* f0    = (const float*)d_in[0];
    const float* f1    = (const float*)d_in[1];
    const float* f2    = (const float*)d_in[2];
    const float* f3    = (const float*)d_in[3];
    const float* boxes = (const float*)d_in[4];
    const int*   bidx  = (const int*)d_in[5];
    float* out = (float*)d_out;

    const int M = in_sizes[5];
    if (ws_size >= WS_NEED) {
        unsigned short* ws = (unsigned short*)d_ws;
        stage_kernel<<<32*M + 2688, 256, 0, stream>>>(f0,f1,f2,f3,boxes,bidx,ws,M);
        pool_nhwc<<<dim3(M, 7), 256, 0, stream>>>(boxes, bidx, ws, out);
    } else {
        roi_pool_direct<<<dim3(M, 8), 256, 0, stream>>>(f0,f1,f2,f3,boxes,bidx,out);
    }
}

// Round 17
// 54.976 us; speedup vs baseline: 1.8905x; 1.0655x over previous
//
#include <hip/hip_runtime.h>
#include <cmath>

// ROIAlignV2 multi-level FPN pooler. fp32 in/out.
// R17: single fused kernel. Block = (box, 16-ch group). Stage the box's
// sample window (<=1088 px, all levels) into a bf16 LDS tile with 16-deep
// gather ILP, pool 196 bins from LDS, write coalesced. No workspace.
constexpr int OUTD = 14;
constexpr int NBIN = OUTD * OUTD;   // 196
constexpr int NS   = 28;            // samples per axis
constexpr int CTOT = 256;           // channels
constexpr int GC   = 16;            // channels per block
constexpr int SLOT = 1088;          // px capacity (worst-case window ~1010)
constexpr int STR  = 18;            // tile row stride in ushorts (36B, 4-aligned)

__device__ inline int box_level(const float* __restrict__ boxes, int m,
                                float& bx0, float& by0, float& bx1, float& by1)
{
    bx0 = boxes[m*4+0]; by0 = boxes[m*4+1];
    bx1 = boxes[m*4+2]; by1 = boxes[m*4+3];
    const float size = sqrtf((bx1-bx0)*(by1-by0));
    float lf = floorf(4.0f + log2f(size/224.0f + 2.220446049250313e-16f));
    lf = fminf(fmaxf(lf, 2.0f), 5.0f);
    return (int)lf - 2;             // 0..3
}

__device__ inline void axis_window(float c0, float c1, int HW, int& lo, int& ext)
{
    const float binw = (c1 - c0) * (1.0f/OUTD);
    const float HWm1 = (float)(HW-1);
    const float pL = fminf(fmaxf(c0 + 0.25f*binw, 0.f), HWm1);   // sample 0
    const float pH = fminf(fmaxf(c0 + 13.75f*binw, 0.f), HWm1);  // sample 27
    const int loL = (int)floorf(pL);
    const int hiH = min((int)floorf(pH) + 1, HW - 1);
    lo = loL;
    ext = hiH - loL + 1;
}

__device__ inline float b2f(unsigned short u) {
    return __uint_as_float(((unsigned int)u) << 16);
}
__device__ inline float b2f_hi(unsigned int u) {      // high half of packed pair
    return __uint_as_float(u & 0xFFFF0000u);
}
__device__ inline float b2f_lo(unsigned int u) {
    return __uint_as_float(u << 16);
}
__device__ inline unsigned short f2b(float x) {       // RTNE
    unsigned int u = __float_as_uint(x);
    return (unsigned short)((u + 0x7FFFu + ((u >> 16) & 1u)) >> 16);
}

__global__ __launch_bounds__(256) void fused_roi_kernel(
    const float* __restrict__ f0, const float* __restrict__ f1,
    const float* __restrict__ f2, const float* __restrict__ f3,
    const float* __restrict__ boxes, const int* __restrict__ bidx,
    float* __restrict__ out)
{
    const int m   = blockIdx.x;
    const int grp = blockIdx.y;         // 16-channel group, 0..15

    float bx0, by0, bx1, by1;
    const int L = box_level(boxes, m, bx0, by0, bx1, by1);
    const int HW = 256 >> L;
    const float scale = (L==0) ? 0.25f : (L==1) ? 0.125f : (L==2) ? 0.0625f : 0.03125f;
    const float* feat = (L==0) ? f0 : (L==1) ? f1 : (L==2) ? f2 : f3;
    const int b = bidx[m];

    int x0, ww, y0, wh;
    axis_window(bx0*scale - 0.5f, bx1*scale - 0.5f, HW, x0, ww);
    axis_window(by0*scale - 0.5f, by1*scale - 0.5f, HW, y0, wh);
    int area = ww * wh;
    if (area > SLOT) { wh = SLOT / ww; area = ww * wh; }   // safety, never hits

    __shared__ unsigned short tile[SLOT * STR];   // [px][16ch], 36B rows
    __shared__ float obuf[GC * 197];              // [16ch][196bin] padded
    __shared__ int4  s_tab[2][NS];                // window-relative taps

    const int t = threadIdx.x;

    // ---- per-sample tap table (window-relative, validity-folded) ----
    if (t < 2*NS) {
        const int axis = t / NS, s = t % NS;
        const float c0 = (axis ? by0 : bx0) * scale - 0.5f;
        const float c1 = (axis ? by1 : bx1) * scale - 0.5f;
        const float binw = (c1 - c0) * (1.0f/OUTD);
        const float g = (float)(s >> 1) + ((s & 1) ? 0.75f : 0.25f);
        const float p = c0 + g * binw;
        const bool valid = (p > -1.0f) && (p < (float)HW);
        const float pc = fminf(fmaxf(p, 0.0f), (float)(HW - 1));
        int lo = (int)floorf(pc);
        int hi = min(lo + 1, HW - 1);
        const float l = pc - (float)lo;
        const int o = axis ? y0 : x0;
        int4 e; e.x = lo - o; e.y = hi - o;
        e.z = __float_as_int(valid ? (1.0f - l) : 0.0f);
        e.w = __float_as_int(valid ? l : 0.0f);
        s_tab[axis][s] = e;
    }

    // ---- stage window: 16-deep gather per px, goff in registers ----
    const int HWsq = HW * HW;
    const float* cb = feat + (size_t)(b*CTOT + grp*GC) * HWsq;
    for (int c0 = 0; c0 < area; c0 += 256) {
        const int px = c0 + t;
        if (px < area) {
            const int row = px / ww;
            const int g = (y0 + row)*HW + x0 + (px - row*ww);
            float v[GC];
            #pragma unroll
            for (int r = 0; r < GC; ++r) v[r] = cb[(size_t)r*HWsq + g];
            unsigned short* tp = &tile[px * STR];
            #pragma unroll
            for (int r = 0; r < GC; ++r) tp[r] = f2b(v[r]);
        }
    }
    __syncthreads();

    // ---- pool from LDS: item = (bin, 4-ch quarter) ----
    for (int it = t; it < NBIN*4; it += 256) {
        const int bin = it >> 2, cq = it & 3;
        const int ph = bin / OUTD, pw = bin - ph*OUTD;
        const int4 ty0 = s_tab[1][2*ph], ty1 = s_tab[1][2*ph+1];
        const int4 tx0 = s_tab[0][2*pw], tx1 = s_tab[0][2*pw+1];
        int ro[4]; float wy[4];
        ro[0]=ty0.x*ww; wy[0]=__int_as_float(ty0.z);
        ro[1]=ty0.y*ww; wy[1]=__int_as_float(ty0.w);
        ro[2]=ty1.x*ww; wy[2]=__int_as_float(ty1.z);
        ro[3]=ty1.y*ww; wy[3]=__int_as_float(ty1.w);
        int co[4]; float wx[4];
        co[0]=tx0.x; wx[0]=__int_as_float(tx0.z);
        co[1]=tx0.y; wx[1]=__int_as_float(tx0.w);
        co[2]=tx1.x; wx[2]=__int_as_float(tx1.z);
        co[3]=tx1.y; wx[3]=__int_as_float(tx1.w);

        float a0=0.f, a1=0.f, a2=0.f, a3=0.f;
        #pragma unroll
        for (int k = 0; k < 16; ++k) {
            const int px = ro[k>>2] + co[k&3];
            const float wt = wy[k>>2] * wx[k&3];
            const unsigned int u0 = *(const unsigned int*)&tile[px*STR + 4*cq];
            const unsigned int u1 = *(const unsigned int*)&tile[px*STR + 4*cq + 2];
            a0 = fmaf(wt, b2f_lo(u0), a0);
            a1 = fmaf(wt, b2f_hi(u0), a1);
            a2 = fmaf(wt, b2f_lo(u1), a2);
            a3 = fmaf(wt, b2f_hi(u1), a3);
        }
        float* ob = &obuf[bin];
        ob[(4*cq+0)*197] = a0 * 0.25f;
        ob[(4*cq+1)*197] = a1 * 0.25f;
        ob[(4*cq+2)*197] = a2 * 0.25f;
        ob[(4*cq+3)*197] = a3 * 0.25f;
    }
    __syncthreads();

    // ---- coalesced output: out channels [grp*16, grp*16+16) of box m ----
    float* dst = out + ((size_t)m*CTOT + grp*GC) * NBIN;
    for (int j = t; j < GC*NBIN; j += 256) {
        const int ch = j / NBIN;
        dst[j] = obuf[ch*197 + (j - ch*NBIN)];
    }
}

extern "C" void kernel_launch(void* const* d_in, const int* in_sizes, int n_in,
                              void* d_out, int out_size, void* d_ws, size_t ws_size,
                              hipStream_t stream) {
    const float* f0    = (const float*)d_in[0];
    const float* f1    = (const float*)d_in[1];
    const float* f2    = (const float*)d_in[2];
    const float* f3    = (const float*)d_in[3];
    const float* boxes = (const float*)d_in[4];
    const int*   bidx  = (const int*)d_in[5];
    float* out = (float*)d_out;

    const int M = in_sizes[5];
    fused_roi_kernel<<<dim3(M, CTOT/GC), 256, 0, stream>>>(
        f0, f1, f2, f3, boxes, bidx, out);
}

// Round 18
// 49.690 us; speedup vs baseline: 2.0916x; 1.1064x over previous
//
#include <hip/hip_runtime.h>
#include <cmath>

// ROIAlignV2 multi-level FPN pooler. fp32 in/out.
// R18: R17 fused kernel with GC=8 (28.5KB LDS -> 5 blocks/CU, 8192 blocks).
// Block = (box, 8-ch group): stage window (<=1088 px) into bf16 LDS tile,
// pool 196 bins from LDS, write coalesced. No workspace.
constexpr int OUTD = 14;
constexpr int NBIN = OUTD * OUTD;   // 196
constexpr int NS   = 28;            // samples per axis
constexpr int CTOT = 256;           // channels
constexpr int GC   = 8;             // channels per block
constexpr int SLOT = 1088;          // px capacity (worst-case window ~1045)
constexpr int STR  = 10;            // tile row stride in ushorts (20B)

__device__ inline int box_level(const float* __restrict__ boxes, int m,
                                float& bx0, float& by0, float& bx1, float& by1)
{
    bx0 = boxes[m*4+0]; by0 = boxes[m*4+1];
    bx1 = boxes[m*4+2]; by1 = boxes[m*4+3];
    const float size = sqrtf((bx1-bx0)*(by1-by0));
    float lf = floorf(4.0f + log2f(size/224.0f + 2.220446049250313e-16f));
    lf = fminf(fmaxf(lf, 2.0f), 5.0f);
    return (int)lf - 2;             // 0..3
}

__device__ inline void axis_window(float c0, float c1, int HW, int& lo, int& ext)
{
    const float binw = (c1 - c0) * (1.0f/OUTD);
    const float HWm1 = (float)(HW-1);
    const float pL = fminf(fmaxf(c0 + 0.25f*binw, 0.f), HWm1);   // sample 0
    const float pH = fminf(fmaxf(c0 + 13.75f*binw, 0.f), HWm1);  // sample 27
    const int loL = (int)floorf(pL);
    const int hiH = min((int)floorf(pH) + 1, HW - 1);
    lo = loL;
    ext = hiH - loL + 1;
}

__device__ inline float b2f_hi(unsigned int u) {      // high half of packed pair
    return __uint_as_float(u & 0xFFFF0000u);
}
__device__ inline float b2f_lo(unsigned int u) {
    return __uint_as_float(u << 16);
}
__device__ inline unsigned short f2b(float x) {       // RTNE
    unsigned int u = __float_as_uint(x);
    return (unsigned short)((u + 0x7FFFu + ((u >> 16) & 1u)) >> 16);
}

__global__ __launch_bounds__(256) void fused_roi_kernel(
    const float* __restrict__ f0, const float* __restrict__ f1,
    const float* __restrict__ f2, const float* __restrict__ f3,
    const float* __restrict__ boxes, const int* __restrict__ bidx,
    float* __restrict__ out)
{
    const int m   = blockIdx.x;
    const int grp = blockIdx.y;         // 8-channel group, 0..31

    float bx0, by0, bx1, by1;
    const int L = box_level(boxes, m, bx0, by0, bx1, by1);
    const int HW = 256 >> L;
    const float scale = (L==0) ? 0.25f : (L==1) ? 0.125f : (L==2) ? 0.0625f : 0.03125f;
    const float* feat = (L==0) ? f0 : (L==1) ? f1 : (L==2) ? f2 : f3;
    const int b = bidx[m];

    int x0, ww, y0, wh;
    axis_window(bx0*scale - 0.5f, bx1*scale - 0.5f, HW, x0, ww);
    axis_window(by0*scale - 0.5f, by1*scale - 0.5f, HW, y0, wh);
    int area = ww * wh;
    if (area > SLOT) { wh = SLOT / ww; area = ww * wh; }   // safety, never hits

    __shared__ unsigned short tile[SLOT * STR];   // [px][8ch], 20B rows
    __shared__ float obuf[GC * 197];              // [8ch][196bin] padded
    __shared__ int4  s_tab[2][NS];                // window-relative taps

    const int t = threadIdx.x;

    // ---- per-sample tap table (window-relative, validity-folded) ----
    if (t < 2*NS) {
        const int axis = t / NS, s = t % NS;
        const float c0 = (axis ? by0 : bx0) * scale - 0.5f;
        const float c1 = (axis ? by1 : bx1) * scale - 0.5f;
        const float binw = (c1 - c0) * (1.0f/OUTD);
        const float g = (float)(s >> 1) + ((s & 1) ? 0.75f : 0.25f);
        const float p = c0 + g * binw;
        const bool valid = (p > -1.0f) && (p < (float)HW);
        const float pc = fminf(fmaxf(p, 0.0f), (float)(HW - 1));
        int lo = (int)floorf(pc);
        int hi = min(lo + 1, HW - 1);
        const float l = pc - (float)lo;
        const int o = axis ? y0 : x0;
        int4 e; e.x = lo - o; e.y = hi - o;
        e.z = __float_as_int(valid ? (1.0f - l) : 0.0f);
        e.w = __float_as_int(valid ? l : 0.0f);
        s_tab[axis][s] = e;
    }

    // ---- stage window: 8-deep gather per px ----
    const int HWsq = HW * HW;
    const float* cb = feat + (size_t)(b*CTOT + grp*GC) * HWsq;
    for (int c0 = 0; c0 < area; c0 += 256) {
        const int px = c0 + t;
        if (px < area) {
            const int row = px / ww;
            const int g = (y0 + row)*HW + x0 + (px - row*ww);
            float v[GC];
            #pragma unroll
            for (int r = 0; r < GC; ++r) v[r] = cb[(size_t)r*HWsq + g];
            unsigned short* tp = &tile[px * STR];
            #pragma unroll
            for (int r = 0; r < GC; ++r) tp[r] = f2b(v[r]);
        }
    }
    __syncthreads();

    // ---- pool from LDS: item = (bin, 4-ch half) ----
    for (int it = t; it < NBIN*2; it += 256) {
        const int bin = it >> 1, cq = it & 1;
        const int ph = bin / OUTD, pw = bin - ph*OUTD;
        const int4 ty0 = s_tab[1][2*ph], ty1 = s_tab[1][2*ph+1];
        const int4 tx0 = s_tab[0][2*pw], tx1 = s_tab[0][2*pw+1];
        int ro[4]; float wy[4];
        ro[0]=ty0.x*ww; wy[0]=__int_as_float(ty0.z);
        ro[1]=ty0.y*ww; wy[1]=__int_as_float(ty0.w);
        ro[2]=ty1.x*ww; wy[2]=__int_as_float(ty1.z);
        ro[3]=ty1.y*ww; wy[3]=__int_as_float(ty1.w);
        int co[4]; float wx[4];
        co[0]=tx0.x; wx[0]=__int_as_float(tx0.z);
        co[1]=tx0.y; wx[1]=__int_as_float(tx0.w);
        co[2]=tx1.x; wx[2]=__int_as_float(tx1.z);
        co[3]=tx1.y; wx[3]=__int_as_float(tx1.w);

        float a0=0.f, a1=0.f, a2=0.f, a3=0.f;
        #pragma unroll
        for (int k = 0; k < 16; ++k) {
            const int px = ro[k>>2] + co[k&3];
            const float wt = wy[k>>2] * wx[k&3];
            const unsigned int u0 = *(const unsigned int*)&tile[px*STR + 4*cq];
            const unsigned int u1 = *(const unsigned int*)&tile[px*STR + 4*cq + 2];
            a0 = fmaf(wt, b2f_lo(u0), a0);
            a1 = fmaf(wt, b2f_hi(u0), a1);
            a2 = fmaf(wt, b2f_lo(u1), a2);
            a3 = fmaf(wt, b2f_hi(u1), a3);
        }
        float* ob = &obuf[bin];
        ob[(4*cq+0)*197] = a0 * 0.25f;
        ob[(4*cq+1)*197] = a1 * 0.25f;
        ob[(4*cq+2)*197] = a2 * 0.25f;
        ob[(4*cq+3)*197] = a3 * 0.25f;
    }
    __syncthreads();

    // ---- coalesced output: out channels [grp*8, grp*8+8) of box m ----
    float* dst = out + ((size_t)m*CTOT + grp*GC) * NBIN;
    for (int j = t; j < GC*NBIN; j += 256) {
        const int ch = j / NBIN;
        dst[j] = obuf[ch*197 + (j - ch*NBIN)];
    }
}

extern "C" void kernel_launch(void* const* d_in, const int* in_sizes, int n_in,
                              void* d_out, int out_size, void* d_ws, size_t ws_size,
                              hipStream_t stream) {
    const float* f0    = (const float*)d_in[0];
    const float* f1    = (const float*)d_in[1];
    const float* f2    = (const float*)d_in[2];
    const float* f3    = (const float*)d_in[3];
    const float* boxes = (const float*)d_in[4];
    const int*   bidx  = (const int*)d_in[5];
    float* out = (float*)d_out;

    const int M = in_sizes[5];
    fused_roi_kernel<<<dim3(M, CTOT/GC), 256, 0, stream>>>(
        f0, f1, f2, f3, boxes, bidx, out);
}